// Round 9
// baseline (223.735 us; speedup 1.0000x reference)
//
#include <hip/hip_runtime.h>

typedef __attribute__((ext_vector_type(8))) short bf16x8;
typedef __attribute__((ext_vector_type(4))) short bf16x4;
typedef __attribute__((ext_vector_type(4))) float f32x4;
typedef __attribute__((ext_vector_type(2))) float f32x2;
typedef __attribute__((ext_vector_type(2))) unsigned u32x2;
typedef __attribute__((ext_vector_type(4))) unsigned u32x4;

#define DEVI static __device__ __forceinline__
#define AS1 __attribute__((address_space(1)))
#define AS3 __attribute__((address_space(3)))

DEVI unsigned short f2bf(float f) {
  unsigned u = __builtin_bit_cast(unsigned, f);
  return (unsigned short)((u + 0x7FFFu + ((u >> 16) & 1u)) >> 16);
}

DEVI unsigned pkbf(float a, float b) {
#if __has_builtin(__builtin_amdgcn_cvt_pk_bf16_f32)
  return __builtin_bit_cast(unsigned, __builtin_amdgcn_cvt_pk_bf16_f32(a, b));
#else
  return (unsigned)f2bf(a) | ((unsigned)f2bf(b) << 16);
#endif
}

DEVI float fast_exp2(float x) {
#if __has_builtin(__builtin_amdgcn_exp2f)
  return __builtin_amdgcn_exp2f(x);
#else
  return exp2f(x);
#endif
}

// async 16B global->LDS; LDS dest = uniform base + lane*16
DEVI void gl_lds16(const unsigned short* g, unsigned short* l) {
  __builtin_amdgcn_global_load_lds((const AS1 unsigned int*)g, (AS3 unsigned int*)l, 16, 0, 0);
}

// fragment-major element offset: [row-tile16][k-granule8][16 rows][8 k]
DEVI size_t frag_off(int row, int k, int KG) {
  return ((size_t)(row >> 4) * KG + (k >> 3)) * 128 + (row & 15) * 8 + (k & 7);
}

// ---------------------------------------------------------------------------
// x fp32 [32768][320] -> bf16 fragment-major, fully coalesced via LDS bounce.
// ---------------------------------------------------------------------------
__global__ __launch_bounds__(256)
void k_prep(const float* __restrict__ x, unsigned short* __restrict__ xf) {
  __shared__ __align__(16) unsigned short L[20480];
  const int t = threadIdx.x;
  const size_t base = (size_t)blockIdx.x * 64 * 320;
#pragma unroll
  for (int i = 0; i < 10; i++) {
    int c = i * 256 + t;  // 16B granule in row-major order: r = c/40, g = c%40
    const float* p = x + base + (size_t)c * 8;
    f32x4 a = ((const f32x4*)p)[0], b = ((const f32x4*)p)[1];
    u32x4 pk = {pkbf(a[0], a[1]), pkbf(a[2], a[3]), pkbf(b[0], b[1]), pkbf(b[2], b[3])};
    int r = c / 40, g = c - r * 40;
    int gidx = ((r >> 4) * 40 + g) * 16 + (r & 15);
    int sidx = gidx ^ ((gidx >> 4) & 7);
    *(u32x4*)(L + sidx * 8) = pk;
  }
  __syncthreads();
  unsigned short* outb = xf + base;  // block's frag-region is contiguous
#pragma unroll
  for (int i = 0; i < 10; i++) {
    int o = i * 256 + t;
    int sidx = o ^ ((o >> 4) & 7);
    *(u32x4*)(outb + (size_t)o * 8) = *(const u32x4*)(L + sidx * 8);
  }
}

// ---------------------------------------------------------------------------
// Weight transposes -> bf16 fragment-major. src fp32 [K][N] -> frag[n][k].
// ---------------------------------------------------------------------------
__global__ __launch_bounds__(256)
void k_transpose_all(const float* __restrict__ q_w, const float* __restrict__ kv_w,
                     const float* __restrict__ proj_w, const float* __restrict__ sr_w,
                     unsigned short* __restrict__ Wq, unsigned short* __restrict__ Wkv,
                     unsigned short* __restrict__ Wp, unsigned short* __restrict__ Wsr) {
  const float* src; unsigned short* dst; int K, N;
  switch (blockIdx.z) {
    case 0:  src = q_w;    dst = Wq;  K = 320;  N = 320; break;
    case 1:  src = kv_w;   dst = Wkv; K = 320;  N = 640; break;
    case 2:  src = proj_w; dst = Wp;  K = 320;  N = 320; break;
    default: src = sr_w;   dst = Wsr; K = 1280; N = 320; break;
  }
  if ((int)blockIdx.x >= (K >> 5) || (int)blockIdx.y >= (N >> 5)) return;
  const int KG = K >> 3;
  __shared__ float tile[32][33];
  const int k0 = blockIdx.x * 32, n0 = blockIdx.y * 32;
  const int tx = threadIdx.x, ty = threadIdx.y;
#pragma unroll
  for (int i = 0; i < 4; i++)
    tile[ty + i * 8][tx] = src[(size_t)(k0 + ty + i * 8) * N + n0 + tx];
  __syncthreads();
#pragma unroll
  for (int i = 0; i < 4; i++) {
    int n = n0 + ty + i * 8, k = k0 + tx;
    dst[frag_off(n, k, KG)] = f2bf(tile[tx][ty + i * 8]);
  }
}

// ---------------------------------------------------------------------------
// LayerNorm: one wave per row of xc[8192][320] -> bf16 frag-major xr
// ---------------------------------------------------------------------------
__global__ __launch_bounds__(256)
void k_ln(const float* __restrict__ xc, const float* __restrict__ gam,
          const float* __restrict__ bet, unsigned short* __restrict__ xr) {
  const int row = blockIdx.x * 4 + (threadIdx.x >> 6);
  const int l = threadIdx.x & 63;
  const float* p = xc + (size_t)row * 320;
  float s = 0.f, ss = 0.f;
#pragma unroll
  for (int i = 0; i < 5; i++) { float v = p[l + 64 * i]; s += v; ss += v * v; }
#pragma unroll
  for (int o = 1; o < 64; o <<= 1) { s += __shfl_xor(s, o); ss += __shfl_xor(ss, o); }
  float mu = s * (1.f / 320.f);
  float var = ss * (1.f / 320.f) - mu * mu;
  float rstd = rsqrtf(var + 1e-5f);
  if (l < 40) {
    f32x4 a = ((const f32x4*)(p + l * 8))[0], b = ((const f32x4*)(p + l * 8))[1];
    f32x4 ga = ((const f32x4*)(gam + l * 8))[0], gb = ((const f32x4*)(gam + l * 8))[1];
    f32x4 ba = ((const f32x4*)(bet + l * 8))[0], bb = ((const f32x4*)(bet + l * 8))[1];
    f32x4 ya, yb;
#pragma unroll
    for (int j = 0; j < 4; j++) {
      ya[j] = (a[j] - mu) * rstd * ga[j] + ba[j];
      yb[j] = (b[j] - mu) * rstd * gb[j] + bb[j];
    }
    u32x4 pk = {pkbf(ya[0], ya[1]), pkbf(ya[2], ya[3]), pkbf(yb[0], yb[1]), pkbf(yb[2], yb[3])};
    *(u32x4*)(xr + ((size_t)((row >> 4) * 40 + l)) * 128 + (row & 15) * 8) = pk;
  }
}

// ---------------------------------------------------------------------------
// Weights-stationary GEMM (R6 geometry — best measured).
// AK: 0 = A frag-major rows;  1 = SR-conv row-remap (NSEG=4 (kh,kw) segments)
// EPI: 3 = fp32 out [M][320]
//      4 = KV merged: n0<320 -> Kb; else Vt [b][h][64][1024] (LDS bounce),
//          kv-permuted so the attention PV A-fragment is one 16B granule.
// ---------------------------------------------------------------------------
template <int MT, int AK, int EPI, int NSEG>
__global__ __launch_bounds__(256)
void k_gemm(const unsigned short* __restrict__ A, const unsigned short* __restrict__ W,
            const float* __restrict__ bias, void* __restrict__ outp, void* __restrict__ outp2,
            float oscale) {
  __shared__ __align__(16) unsigned short Bl[20480];  // 40 KB
  const int t = threadIdx.x, w = t >> 6, ln = t & 63, lr = ln & 15, lq = ln >> 4;
  const int m0 = blockIdx.x * (MT * 64), n0 = blockIdx.y * 64;

  f32x4 acc[MT][4];
#pragma unroll
  for (int i = 0; i < MT; i++)
#pragma unroll
    for (int j = 0; j < 4; j++) acc[i][j] = (f32x4){0.f, 0.f, 0.f, 0.f};

#pragma unroll
  for (int seg = 0; seg < NSEG; seg++) {
    const int kh = seg >> 1, kw = seg & 1;
    if (seg) __syncthreads();
    if (AK == 0) {
      const unsigned short* Ws = W + ((size_t)(n0 >> 4) * 40) * 128;
#pragma unroll
      for (int j = 0; j < 10; j++)
        gl_lds16(Ws + (size_t)(j * 4 + w) * 512 + ln * 8, Bl + (j * 4 + w) * 512);
    } else {
      const unsigned short* Wt = W + ((size_t)((n0 >> 4) + w) * 160 + seg * 40) * 128;
#pragma unroll
      for (int j = 0; j < 10; j++)
        gl_lds16(Wt + (size_t)j * 512 + ln * 8, Bl + w * 5120 + j * 512);
    }
    __syncthreads();

#pragma unroll
    for (int ks = 0; ks < 10; ks++) {
      bf16x8 af[MT], bfr[4];
#pragma unroll
      for (int mi = 0; mi < MT; mi++) {
        if (AK == 0) {
          af[mi] = *(const bf16x8*)(
              A + ((size_t)((m0 >> 4) + w * MT + mi) * 40 + ks * 4 + lq) * 128 + lr * 8);
        } else {
          int gm = m0 + (w * MT + mi) * 16;
          int b = gm >> 10, p = gm & 1023, oy = p >> 5, ox0 = p & 31;
          int r0 = (2 * oy + kh) * 64 + 2 * ox0 + kw;           // r0 & 15 == kw
          int brt = b * 256 + (r0 >> 4);
          af[mi] = *(const bf16x8*)(
              A + ((size_t)(brt + (lr >> 3)) * 40 + ks * 4 + lq) * 128 +
              (kw + 2 * (lr & 7)) * 8);
        }
      }
#pragma unroll
      for (int ni = 0; ni < 4; ni++)
        bfr[ni] = *(const bf16x8*)(Bl + ((ni * 40) + ks * 4 + lq) * 128 + lr * 8);
#pragma unroll
      for (int mi = 0; mi < MT; mi++)
#pragma unroll
        for (int ni = 0; ni < 4; ni++)
          acc[mi][ni] =
              __builtin_amdgcn_mfma_f32_16x16x32_bf16(af[mi], bfr[ni], acc[mi][ni], 0, 0, 0);
    }
  }

  if (EPI == 3) {  // fp32 [M][320]
    float* out = (float*)outp;
#pragma unroll
    for (int mi = 0; mi < MT; mi++)
#pragma unroll
      for (int ni = 0; ni < 4; ni++)
#pragma unroll
        for (int rr = 0; rr < 4; rr++) {
          int gm = m0 + (w * MT + mi) * 16 + lq * 4 + rr;
          int gc = n0 + ni * 16 + lr;
          out[(size_t)gm * 320 + gc] = acc[mi][ni][rr] + bias[gc];
        }
  } else {  // EPI == 4: KV merged
    if (n0 < 320) {  // K -> [b][h][1024][64]
      unsigned short* out = (unsigned short*)outp;
      const int h = n0 >> 6;
#pragma unroll
      for (int mi = 0; mi < MT; mi++)
#pragma unroll
        for (int ni = 0; ni < 4; ni++)
#pragma unroll
          for (int rr = 0; rr < 4; rr++) {
            int gm = m0 + (w * MT + mi) * 16 + lq * 4 + rr;
            int b = gm >> 10, mm = gm & 1023, d = ni * 16 + lr;
            out[((size_t)(b * 5 + h) << 16) + ((size_t)mm << 6) + d] =
                f2bf(acc[mi][ni][rr] + bias[n0 + d]);
          }
    } else {  // V -> [b][h][64][1024] via LDS bounce (block = MT*64 rows)
      unsigned short* out = (unsigned short*)outp2;
      const int h = (n0 - 320) >> 6;
      const int LDT = MT * 64 + 8;
      unsigned short* Tl = (unsigned short*)Bl;  // [64][LDT]
      __syncthreads();
#pragma unroll
      for (int mi = 0; mi < MT; mi++)
#pragma unroll
        for (int ni = 0; ni < 4; ni++)
#pragma unroll
          for (int rr = 0; rr < 4; rr++) {
            int ml = (w * MT + mi) * 16 + lq * 4 + rr;  // 0..MT*64-1
            int d = ni * 16 + lr;
            Tl[d * LDT + ml] = f2bf(acc[mi][ni][rr] + bias[n0 + d]);
          }
      __syncthreads();
      const int b = m0 >> 10, mm0 = m0 & 1023;
#pragma unroll
      for (int i = 0; i < 2 * MT; i++) {
        int ch = t + 256 * i, d = ch / (8 * MT), g = ch % (8 * MT);
        int c2 = g >> 2, ns = g & 3;  // kv-permute: {4-elem lo, 4-elem hi}
        const unsigned short* src = Tl + d * LDT + c2 * 32 + ns * 4;
        bf16x4 lo = *(const bf16x4*)(src);
        bf16x4 hi = *(const bf16x4*)(src + 16);
        bf16x8 v8 = {lo[0], lo[1], lo[2], lo[3], hi[0], hi[1], hi[2], hi[3]};
        *(bf16x8*)(out + ((size_t)(b * 5 + h) << 16) + d * 1024 + mm0 + g * 8) = v8;
      }
    }
  }
}

// ---------------------------------------------------------------------------
// Attention with fused Q projection; wave Q-tile widened to 64 rows (MTQ=4).
// LDS K/V reads per CU halve (same reads serve 2x MFMA); 2x ILP per chunk.
// Phase 1: Wq stage (40 KB).  Phase 2: Q = x@Wq^T (64x64/wave, 160 MFMA).
// Phase 3: bias+scale -> bf16 via 32 KB swizzled LDS transpose -> qf.
// Phase 4: double-buffered KV loop, 64 MFMA/chunk/wave.
// ---------------------------------------------------------------------------
__global__ __launch_bounds__(256, 2)
void k_attn(const unsigned short* __restrict__ Xf, const unsigned short* __restrict__ Wq,
            const float* __restrict__ q_b,
            const unsigned short* __restrict__ Kb, const unsigned short* __restrict__ Vt,
            unsigned short* __restrict__ AO) {
  __shared__ __align__(16) unsigned char smem[40960];  // Wq 40KB / Ql 32KB / KV 2x16KB
  const int t = threadIdx.x, w = t >> 6, ln = t & 63, lr = ln & 15, lq = ln >> 4;
  const int bh = blockIdx.y;
  const int b = bh / 5, h = bh - b * 5;
  const int m0 = blockIdx.x * 256 + w * 64;  // local row within (b, ...)
  const unsigned short* Kp = Kb + ((size_t)bh << 16);
  const unsigned short* Vp = Vt + ((size_t)bh << 16);
  const float S2 = 0.125f * 1.4426950408889634f;  // SCALE * log2(e)

  // ---- Phase 1: stage Wq h-slice (64 cols x 320 k, frag-major, 40 KB) ----
  unsigned short* Bl = (unsigned short*)smem;
  {
    const unsigned short* Ws = Wq + ((size_t)(h * 4) * 40) * 128;
#pragma unroll
    for (int j = 0; j < 10; j++)
      gl_lds16(Ws + (size_t)(j * 4 + w) * 512 + ln * 8, Bl + (j * 4 + w) * 512);
  }
  __syncthreads();

  // ---- Phase 2: Q tile (64 rows x 64 cols per wave) ----
  f32x4 qacc[4][4];
#pragma unroll
  for (int mi = 0; mi < 4; mi++)
#pragma unroll
    for (int ni = 0; ni < 4; ni++) qacc[mi][ni] = (f32x4){0.f, 0.f, 0.f, 0.f};
  const int rtb = b * 256 + (m0 >> 4);  // global row-tile of xf
#pragma unroll
  for (int ks = 0; ks < 10; ks++) {
    bf16x8 af[4], bfr[4];
#pragma unroll
    for (int mi = 0; mi < 4; mi++)
      af[mi] = *(const bf16x8*)(Xf + ((size_t)(rtb + mi) * 40 + ks * 4 + lq) * 128 + lr * 8);
#pragma unroll
    for (int ni = 0; ni < 4; ni++)
      bfr[ni] = *(const bf16x8*)(Bl + ((ni * 40) + ks * 4 + lq) * 128 + lr * 8);
#pragma unroll
    for (int mi = 0; mi < 4; mi++)
#pragma unroll
      for (int ni = 0; ni < 4; ni++)
        qacc[mi][ni] =
            __builtin_amdgcn_mfma_f32_16x16x32_bf16(af[mi], bfr[ni], qacc[mi][ni], 0, 0, 0);
  }
  __syncthreads();  // all Wq reads done before Ql overwrites the region

  // ---- Phase 3: bias+scale -> bf16, swizzled LDS transpose -> qf ----
  unsigned short* Ql = (unsigned short*)smem;  // [256][64], 32 KB
  float qbv[4];
#pragma unroll
  for (int ni = 0; ni < 4; ni++) qbv[ni] = q_b[h * 64 + ni * 16 + lr];
#pragma unroll
  for (int mt = 0; mt < 4; mt++)
#pragma unroll
    for (int ni = 0; ni < 4; ni++)
#pragma unroll
      for (int rr = 0; rr < 4; rr++) {
        int row = w * 64 + mt * 16 + lq * 4 + rr;
        int col = ni * 16 + lr;
        float qv = (qacc[mt][ni][rr] + qbv[ni]) * S2;
        Ql[row * 64 + (((col >> 3) ^ (row & 7)) * 8) + (col & 7)] = f2bf(qv);
      }
  __syncthreads();
  bf16x8 qf[4][2];
#pragma unroll
  for (int mt = 0; mt < 4; mt++)
#pragma unroll
    for (int t2 = 0; t2 < 2; t2++) {
      int row = w * 64 + mt * 16 + lr;
      qf[mt][t2] = *(const bf16x8*)(Ql + row * 64 + (((t2 * 4 + lq) ^ (lr & 7)) * 8));
    }
  __syncthreads();  // qf reads done before KV staging reuses smem

  // ---- Phase 4: KV loop ----
  f32x4 oacc[4][4];
  f32x2 den2[4];
#pragma unroll
  for (int mt = 0; mt < 4; mt++) den2[mt] = (f32x2){0.f, 0.f};
#pragma unroll
  for (int dt = 0; dt < 4; dt++)
#pragma unroll
    for (int mt = 0; mt < 4; mt++) oacc[dt][mt] = (f32x4){0.f, 0.f, 0.f, 0.f};

  const int rS = ln >> 3, sS = ln & 7;

  auto stage = [&](int c, int buf) {
    unsigned short* KL = (unsigned short*)(smem + buf * 16384);
    unsigned short* VL = KL + 4096;
#pragma unroll
    for (int i = 0; i < 2; i++) {
      int r = (w * 2 + i) * 8 + rS;
      int g = sS ^ (r & 7);
      gl_lds16(Kp + (size_t)(c * 64 + r) * 64 + g * 8, KL + (w * 2 + i) * 512);
      gl_lds16(Vp + (size_t)r * 1024 + c * 64 + g * 8, VL + (w * 2 + i) * 512);
    }
  };

  stage(0, 0);
  __syncthreads();

  for (int c = 0; c < 16; c++) {
    if (c < 15) stage(c + 1, (c + 1) & 1);
    const unsigned short* KL = (const unsigned short*)(smem + (c & 1) * 16384);
    const unsigned short* VL = KL + 4096;

    // tp-split: compute 2 kt-tiles of S^T, exp+pack, PV — then the next 2.
#pragma unroll
    for (int tp = 0; tp < 2; tp++) {
      f32x4 sacc[2][4];
#pragma unroll
      for (int k2 = 0; k2 < 2; k2++) {
        int kt = 2 * tp + k2;
        int kr = 16 * kt + lr;
        bf16x8 kf0 = *(const bf16x8*)(KL + kr * 64 + ((lq ^ (lr & 7)) * 8));
        bf16x8 kf1 = *(const bf16x8*)(KL + kr * 64 + (((4 + lq) ^ (lr & 7)) * 8));
        __builtin_amdgcn_s_setprio(1);
#pragma unroll
        for (int mt = 0; mt < 4; mt++) {
          f32x4 s = (f32x4){0.f, 0.f, 0.f, 0.f};
          s = __builtin_amdgcn_mfma_f32_16x16x32_bf16(kf0, qf[mt][0], s, 0, 0, 0);
          s = __builtin_amdgcn_mfma_f32_16x16x32_bf16(kf1, qf[mt][1], s, 0, 0, 0);
          sacc[k2][mt] = s;
        }
        __builtin_amdgcn_s_setprio(0);
      }

      bf16x8 pf8[4];
#pragma unroll
      for (int mt = 0; mt < 4; mt++) {
        f32x4 ea, eb;
#pragma unroll
        for (int j = 0; j < 4; j++) {
          ea[j] = fast_exp2(sacc[0][mt][j]);
          eb[j] = fast_exp2(sacc[1][mt][j]);
        }
        den2[mt] += (f32x2){ea[0], ea[1]} + (f32x2){ea[2], ea[3]};
        den2[mt] += (f32x2){eb[0], eb[1]} + (f32x2){eb[2], eb[3]};
        u32x4 pk = {pkbf(ea[0], ea[1]), pkbf(ea[2], ea[3]),
                    pkbf(eb[0], eb[1]), pkbf(eb[2], eb[3])};
        pf8[mt] = __builtin_bit_cast(bf16x8, pk);
      }
#pragma unroll
      for (int dt = 0; dt < 4; dt++) {
        int vr = dt * 16 + lr;
        bf16x8 vf8 = *(const bf16x8*)(VL + vr * 64 + (((4 * tp + lq) ^ (lr & 7)) * 8));
        __builtin_amdgcn_s_setprio(1);
#pragma unroll
        for (int mt = 0; mt < 4; mt++)
          oacc[dt][mt] =
              __builtin_amdgcn_mfma_f32_16x16x32_bf16(vf8, pf8[mt], oacc[dt][mt], 0, 0, 0);
        __builtin_amdgcn_s_setprio(0);
      }
    }
    __syncthreads();
  }

  float inv[4];
#pragma unroll
  for (int mt = 0; mt < 4; mt++) {
    float s = den2[mt][0] + den2[mt][1];
    s += __shfl_xor(s, 16);
    s += __shfl_xor(s, 32);
    inv[mt] = 1.f / s;
  }

  const int rt0 = b * 256 + (m0 >> 4);
#pragma unroll
  for (int mt = 0; mt < 4; mt++)
#pragma unroll
    for (int dt = 0; dt < 4; dt++) {
      float i0 = inv[mt];
      u32x2 pk = {pkbf(oacc[dt][mt][0] * i0, oacc[dt][mt][1] * i0),
                  pkbf(oacc[dt][mt][2] * i0, oacc[dt][mt][3] * i0)};
      int colg = h * 8 + dt * 2 + (lq >> 1);
      size_t off = ((size_t)(rt0 + mt) * 40 + colg) * 128 + lr * 8 + (lq & 1) * 4;
      *(u32x2*)(AO + off) = pk;
    }
}

// ---------------------------------------------------------------------------
extern "C" void kernel_launch(void* const* d_in, const int* in_sizes, int n_in,
                              void* d_out, int out_size, void* d_ws, size_t ws_size,
                              hipStream_t stream) {
  (void)in_sizes; (void)n_in; (void)out_size; (void)ws_size;
  const float* x      = (const float*)d_in[0];
  const float* q_w    = (const float*)d_in[1];
  const float* q_b    = (const float*)d_in[2];
  const float* kv_w   = (const float*)d_in[3];
  const float* kv_b   = (const float*)d_in[4];
  const float* sr_w   = (const float*)d_in[5];
  const float* sr_b   = (const float*)d_in[6];
  const float* ln_g   = (const float*)d_in[7];
  const float* ln_b   = (const float*)d_in[8];
  const float* proj_w = (const float*)d_in[9];
  const float* proj_b = (const float*)d_in[10];
  float* out = (float*)d_out;

  char* ws = (char*)d_ws;
  size_t off = 0;
  auto alloc = [&](size_t bytes) {
    void* p = ws + off;
    off += (bytes + 255) & ~(size_t)255;
    return p;
  };
  unsigned short* xbf_fr = (unsigned short*)alloc((size_t)32768 * 320 * 2);
  unsigned short* AO     = (unsigned short*)alloc((size_t)32768 * 320 * 2);
  unsigned short* KbP    = (unsigned short*)alloc((size_t)40 * 65536 * 2);
  unsigned short* VtP    = (unsigned short*)alloc((size_t)40 * 65536 * 2);
  float*          xc     = (float*)alloc((size_t)8192 * 320 * 4);
  unsigned short* xr     = (unsigned short*)alloc((size_t)8192 * 320 * 2);
  unsigned short* Wq_fr  = (unsigned short*)alloc((size_t)320 * 320 * 2);
  unsigned short* Wkv_fr = (unsigned short*)alloc((size_t)640 * 320 * 2);
  unsigned short* Wp_fr  = (unsigned short*)alloc((size_t)320 * 320 * 2);
  unsigned short* Wsr_fr = (unsigned short*)alloc((size_t)320 * 1280 * 2);

  k_prep<<<512, 256, 0, stream>>>(x, xbf_fr);
  k_transpose_all<<<dim3(40, 20, 4), dim3(32, 8), 0, stream>>>(
      q_w, kv_w, proj_w, sr_w, Wq_fr, Wkv_fr, Wp_fr, Wsr_fr);

  // SR conv: M=8192, MT=2 -> 128 rows/block, 4 (kh,kw) segments (R6 geometry)
  k_gemm<2, 1, 3, 4><<<dim3(64, 5), 256, 0, stream>>>(xbf_fr, Wsr_fr, sr_b, xc, nullptr, 1.f);
  k_ln<<<2048, 256, 0, stream>>>(xc, ln_g, ln_b, xr);
  // KV: M=8192, MT=2 (R6 geometry)
  k_gemm<2, 0, 4, 1><<<dim3(64, 10), 256, 0, stream>>>(xr, Wkv_fr, kv_b, KbP, VtP, 1.f);
  k_attn<<<dim3(16, 40), 256, 0, stream>>>(xbf_fr, Wq_fr, q_b, KbP, VtP, AO);
  // proj: M=32768, MT=4 (R6 geometry)
  k_gemm<4, 0, 3, 1><<<dim3(128, 5), 256, 0, stream>>>(AO, Wp_fr, proj_b, out, nullptr, 1.f);
}

// Round 10
// 214.138 us; speedup vs baseline: 1.0448x; 1.0448x over previous
//
#include <hip/hip_runtime.h>

typedef __attribute__((ext_vector_type(8))) short bf16x8;
typedef __attribute__((ext_vector_type(4))) short bf16x4;
typedef __attribute__((ext_vector_type(4))) float f32x4;
typedef __attribute__((ext_vector_type(2))) float f32x2;
typedef __attribute__((ext_vector_type(2))) unsigned u32x2;
typedef __attribute__((ext_vector_type(4))) unsigned u32x4;

#define DEVI static __device__ __forceinline__
#define AS1 __attribute__((address_space(1)))
#define AS3 __attribute__((address_space(3)))

DEVI unsigned short f2bf(float f) {
  unsigned u = __builtin_bit_cast(unsigned, f);
  return (unsigned short)((u + 0x7FFFu + ((u >> 16) & 1u)) >> 16);
}

DEVI unsigned pkbf(float a, float b) {
#if __has_builtin(__builtin_amdgcn_cvt_pk_bf16_f32)
  return __builtin_bit_cast(unsigned, __builtin_amdgcn_cvt_pk_bf16_f32(a, b));
#else
  return (unsigned)f2bf(a) | ((unsigned)f2bf(b) << 16);
#endif
}

DEVI float fast_exp2(float x) {
#if __has_builtin(__builtin_amdgcn_exp2f)
  return __builtin_amdgcn_exp2f(x);
#else
  return exp2f(x);
#endif
}

// async 16B global->LDS; LDS dest = uniform base + lane*16
DEVI void gl_lds16(const unsigned short* g, unsigned short* l) {
  __builtin_amdgcn_global_load_lds((const AS1 unsigned int*)g, (AS3 unsigned int*)l, 16, 0, 0);
}

// fragment-major element offset: [row-tile16][k-granule8][16 rows][8 k]
DEVI size_t frag_off(int row, int k, int KG) {
  return ((size_t)(row >> 4) * KG + (k >> 3)) * 128 + (row & 15) * 8 + (k & 7);
}

// ---------------------------------------------------------------------------
// x fp32 [32768][320] -> bf16 fragment-major, fully coalesced via LDS bounce.
// ---------------------------------------------------------------------------
__global__ __launch_bounds__(256)
void k_prep(const float* __restrict__ x, unsigned short* __restrict__ xf) {
  __shared__ __align__(16) unsigned short L[20480];
  const int t = threadIdx.x;
  const size_t base = (size_t)blockIdx.x * 64 * 320;
#pragma unroll
  for (int i = 0; i < 10; i++) {
    int c = i * 256 + t;  // 16B granule in row-major order: r = c/40, g = c%40
    const float* p = x + base + (size_t)c * 8;
    f32x4 a = ((const f32x4*)p)[0], b = ((const f32x4*)p)[1];
    u32x4 pk = {pkbf(a[0], a[1]), pkbf(a[2], a[3]), pkbf(b[0], b[1]), pkbf(b[2], b[3])};
    int r = c / 40, g = c - r * 40;
    int gidx = ((r >> 4) * 40 + g) * 16 + (r & 15);
    int sidx = gidx ^ ((gidx >> 4) & 7);
    *(u32x4*)(L + sidx * 8) = pk;
  }
  __syncthreads();
  unsigned short* outb = xf + base;  // block's frag-region is contiguous
#pragma unroll
  for (int i = 0; i < 10; i++) {
    int o = i * 256 + t;
    int sidx = o ^ ((o >> 4) & 7);
    *(u32x4*)(outb + (size_t)o * 8) = *(const u32x4*)(L + sidx * 8);
  }
}

// ---------------------------------------------------------------------------
// Weight transposes -> bf16 fragment-major. src fp32 [K][N] -> frag[n][k].
// ---------------------------------------------------------------------------
__global__ __launch_bounds__(256)
void k_transpose_all(const float* __restrict__ q_w, const float* __restrict__ kv_w,
                     const float* __restrict__ proj_w, const float* __restrict__ sr_w,
                     unsigned short* __restrict__ Wq, unsigned short* __restrict__ Wkv,
                     unsigned short* __restrict__ Wp, unsigned short* __restrict__ Wsr) {
  const float* src; unsigned short* dst; int K, N;
  switch (blockIdx.z) {
    case 0:  src = q_w;    dst = Wq;  K = 320;  N = 320; break;
    case 1:  src = kv_w;   dst = Wkv; K = 320;  N = 640; break;
    case 2:  src = proj_w; dst = Wp;  K = 320;  N = 320; break;
    default: src = sr_w;   dst = Wsr; K = 1280; N = 320; break;
  }
  if ((int)blockIdx.x >= (K >> 5) || (int)blockIdx.y >= (N >> 5)) return;
  const int KG = K >> 3;
  __shared__ float tile[32][33];
  const int k0 = blockIdx.x * 32, n0 = blockIdx.y * 32;
  const int tx = threadIdx.x, ty = threadIdx.y;
#pragma unroll
  for (int i = 0; i < 4; i++)
    tile[ty + i * 8][tx] = src[(size_t)(k0 + ty + i * 8) * N + n0 + tx];
  __syncthreads();
#pragma unroll
  for (int i = 0; i < 4; i++) {
    int n = n0 + ty + i * 8, k = k0 + tx;
    dst[frag_off(n, k, KG)] = f2bf(tile[tx][ty + i * 8]);
  }
}

// ---------------------------------------------------------------------------
// LayerNorm: one wave per row of xc[8192][320] -> bf16 frag-major xr
// ---------------------------------------------------------------------------
__global__ __launch_bounds__(256)
void k_ln(const float* __restrict__ xc, const float* __restrict__ gam,
          const float* __restrict__ bet, unsigned short* __restrict__ xr) {
  const int row = blockIdx.x * 4 + (threadIdx.x >> 6);
  const int l = threadIdx.x & 63;
  const float* p = xc + (size_t)row * 320;
  float s = 0.f, ss = 0.f;
#pragma unroll
  for (int i = 0; i < 5; i++) { float v = p[l + 64 * i]; s += v; ss += v * v; }
#pragma unroll
  for (int o = 1; o < 64; o <<= 1) { s += __shfl_xor(s, o); ss += __shfl_xor(ss, o); }
  float mu = s * (1.f / 320.f);
  float var = ss * (1.f / 320.f) - mu * mu;
  float rstd = rsqrtf(var + 1e-5f);
  if (l < 40) {
    f32x4 a = ((const f32x4*)(p + l * 8))[0], b = ((const f32x4*)(p + l * 8))[1];
    f32x4 ga = ((const f32x4*)(gam + l * 8))[0], gb = ((const f32x4*)(gam + l * 8))[1];
    f32x4 ba = ((const f32x4*)(bet + l * 8))[0], bb = ((const f32x4*)(bet + l * 8))[1];
    f32x4 ya, yb;
#pragma unroll
    for (int j = 0; j < 4; j++) {
      ya[j] = (a[j] - mu) * rstd * ga[j] + ba[j];
      yb[j] = (b[j] - mu) * rstd * gb[j] + bb[j];
    }
    u32x4 pk = {pkbf(ya[0], ya[1]), pkbf(ya[2], ya[3]), pkbf(yb[0], yb[1]), pkbf(yb[2], yb[3])};
    *(u32x4*)(xr + ((size_t)((row >> 4) * 40 + l)) * 128 + (row & 15) * 8) = pk;
  }
}

// ---------------------------------------------------------------------------
// Weights-stationary GEMM (R6 geometry — best measured).
// AK: 0 = A frag-major rows;  1 = SR-conv row-remap (NSEG=4 (kh,kw) segments)
// EPI: 3 = fp32 out [M][320]
//      4 = KV merged: n0<320 -> Kb; else Vt [b][h][64][1024] (LDS bounce),
//          kv-permuted so the attention PV A-fragment is one 16B granule.
// ---------------------------------------------------------------------------
template <int MT, int AK, int EPI, int NSEG>
__global__ __launch_bounds__(256)
void k_gemm(const unsigned short* __restrict__ A, const unsigned short* __restrict__ W,
            const float* __restrict__ bias, void* __restrict__ outp, void* __restrict__ outp2,
            float oscale) {
  __shared__ __align__(16) unsigned short Bl[20480];  // 40 KB
  const int t = threadIdx.x, w = t >> 6, ln = t & 63, lr = ln & 15, lq = ln >> 4;
  const int m0 = blockIdx.x * (MT * 64), n0 = blockIdx.y * 64;

  f32x4 acc[MT][4];
#pragma unroll
  for (int i = 0; i < MT; i++)
#pragma unroll
    for (int j = 0; j < 4; j++) acc[i][j] = (f32x4){0.f, 0.f, 0.f, 0.f};

#pragma unroll
  for (int seg = 0; seg < NSEG; seg++) {
    const int kh = seg >> 1, kw = seg & 1;
    if (seg) __syncthreads();
    if (AK == 0) {
      const unsigned short* Ws = W + ((size_t)(n0 >> 4) * 40) * 128;
#pragma unroll
      for (int j = 0; j < 10; j++)
        gl_lds16(Ws + (size_t)(j * 4 + w) * 512 + ln * 8, Bl + (j * 4 + w) * 512);
    } else {
      const unsigned short* Wt = W + ((size_t)((n0 >> 4) + w) * 160 + seg * 40) * 128;
#pragma unroll
      for (int j = 0; j < 10; j++)
        gl_lds16(Wt + (size_t)j * 512 + ln * 8, Bl + w * 5120 + j * 512);
    }
    __syncthreads();

#pragma unroll
    for (int ks = 0; ks < 10; ks++) {
      bf16x8 af[MT], bfr[4];
#pragma unroll
      for (int mi = 0; mi < MT; mi++) {
        if (AK == 0) {
          af[mi] = *(const bf16x8*)(
              A + ((size_t)((m0 >> 4) + w * MT + mi) * 40 + ks * 4 + lq) * 128 + lr * 8);
        } else {
          int gm = m0 + (w * MT + mi) * 16;
          int b = gm >> 10, p = gm & 1023, oy = p >> 5, ox0 = p & 31;
          int r0 = (2 * oy + kh) * 64 + 2 * ox0 + kw;           // r0 & 15 == kw
          int brt = b * 256 + (r0 >> 4);
          af[mi] = *(const bf16x8*)(
              A + ((size_t)(brt + (lr >> 3)) * 40 + ks * 4 + lq) * 128 +
              (kw + 2 * (lr & 7)) * 8);
        }
      }
#pragma unroll
      for (int ni = 0; ni < 4; ni++)
        bfr[ni] = *(const bf16x8*)(Bl + ((ni * 40) + ks * 4 + lq) * 128 + lr * 8);
#pragma unroll
      for (int mi = 0; mi < MT; mi++)
#pragma unroll
        for (int ni = 0; ni < 4; ni++)
          acc[mi][ni] =
              __builtin_amdgcn_mfma_f32_16x16x32_bf16(af[mi], bfr[ni], acc[mi][ni], 0, 0, 0);
    }
  }

  if (EPI == 3) {  // fp32 [M][320]
    float* out = (float*)outp;
#pragma unroll
    for (int mi = 0; mi < MT; mi++)
#pragma unroll
      for (int ni = 0; ni < 4; ni++)
#pragma unroll
        for (int rr = 0; rr < 4; rr++) {
          int gm = m0 + (w * MT + mi) * 16 + lq * 4 + rr;
          int gc = n0 + ni * 16 + lr;
          out[(size_t)gm * 320 + gc] = acc[mi][ni][rr] + bias[gc];
        }
  } else {  // EPI == 4: KV merged
    if (n0 < 320) {  // K -> [b][h][1024][64]
      unsigned short* out = (unsigned short*)outp;
      const int h = n0 >> 6;
#pragma unroll
      for (int mi = 0; mi < MT; mi++)
#pragma unroll
        for (int ni = 0; ni < 4; ni++)
#pragma unroll
          for (int rr = 0; rr < 4; rr++) {
            int gm = m0 + (w * MT + mi) * 16 + lq * 4 + rr;
            int b = gm >> 10, mm = gm & 1023, d = ni * 16 + lr;
            out[((size_t)(b * 5 + h) << 16) + ((size_t)mm << 6) + d] =
                f2bf(acc[mi][ni][rr] + bias[n0 + d]);
          }
    } else {  // V -> [b][h][64][1024] via LDS bounce (block = MT*64 rows)
      unsigned short* out = (unsigned short*)outp2;
      const int h = (n0 - 320) >> 6;
      const int LDT = MT * 64 + 8;
      unsigned short* Tl = (unsigned short*)Bl;  // [64][LDT]
      __syncthreads();
#pragma unroll
      for (int mi = 0; mi < MT; mi++)
#pragma unroll
        for (int ni = 0; ni < 4; ni++)
#pragma unroll
          for (int rr = 0; rr < 4; rr++) {
            int ml = (w * MT + mi) * 16 + lq * 4 + rr;  // 0..MT*64-1
            int d = ni * 16 + lr;
            Tl[d * LDT + ml] = f2bf(acc[mi][ni][rr] + bias[n0 + d]);
          }
      __syncthreads();
      const int b = m0 >> 10, mm0 = m0 & 1023;
#pragma unroll
      for (int i = 0; i < 2 * MT; i++) {
        int ch = t + 256 * i, d = ch / (8 * MT), g = ch % (8 * MT);
        int c2 = g >> 2, ns = g & 3;  // kv-permute: {4-elem lo, 4-elem hi}
        const unsigned short* src = Tl + d * LDT + c2 * 32 + ns * 4;
        bf16x4 lo = *(const bf16x4*)(src);
        bf16x4 hi = *(const bf16x4*)(src + 16);
        bf16x8 v8 = {lo[0], lo[1], lo[2], lo[3], hi[0], hi[1], hi[2], hi[3]};
        *(bf16x8*)(out + ((size_t)(b * 5 + h) << 16) + d * 1024 + mm0 + g * 8) = v8;
      }
    }
  }
}

// ---------------------------------------------------------------------------
// Attention with FUSED Q projection (R6 champion configuration).
// Phase 1: stage Wq h-slice (40 KB) like k_gemm.   Phase 2: Q = x @ Wq^T
// (wave tile 32x64, 80 MFMA).  Phase 3: (acc+bias)*S2 -> bf16 via swizzled
// 16 KB LDS transpose -> qf registers.  Phase 4: double-buffered KV loop
// (LDS reused), tp-split QK, VALU denominator, 48-52 VGPR.
// Measured: 69 µs, Occ ~30%, conflicts 0. Perturbations all worse:
// 3-buf vmcnt pipeline (R4 +9µs), no-LDS direct (R3 +99µs), MTQ=4 (R9 +12µs).
// ---------------------------------------------------------------------------
__global__ __launch_bounds__(256, 4)
void k_attn(const unsigned short* __restrict__ Xf, const unsigned short* __restrict__ Wq,
            const float* __restrict__ q_b,
            const unsigned short* __restrict__ Kb, const unsigned short* __restrict__ Vt,
            unsigned short* __restrict__ AO) {
  __shared__ __align__(16) unsigned char smem[40960];  // Wq 40KB / Ql 16KB / KV 2x16KB
  const int t = threadIdx.x, w = t >> 6, ln = t & 63, lr = ln & 15, lq = ln >> 4;
  const int bh = blockIdx.y;
  const int b = bh / 5, h = bh - b * 5;
  const int m0 = blockIdx.x * 128 + w * 32;  // local row within (b, ...)
  const unsigned short* Kp = Kb + ((size_t)bh << 16);
  const unsigned short* Vp = Vt + ((size_t)bh << 16);
  const float S2 = 0.125f * 1.4426950408889634f;  // SCALE * log2(e)

  // ---- Phase 1: stage Wq h-slice (64 cols x 320 k, frag-major, 40 KB) ----
  unsigned short* Bl = (unsigned short*)smem;
  {
    const unsigned short* Ws = Wq + ((size_t)(h * 4) * 40) * 128;
#pragma unroll
    for (int j = 0; j < 10; j++)
      gl_lds16(Ws + (size_t)(j * 4 + w) * 512 + ln * 8, Bl + (j * 4 + w) * 512);
  }
  __syncthreads();

  // ---- Phase 2: Q tile (32 rows x 64 cols per wave) ----
  f32x4 qacc[2][4];
#pragma unroll
  for (int mi = 0; mi < 2; mi++)
#pragma unroll
    for (int ni = 0; ni < 4; ni++) qacc[mi][ni] = (f32x4){0.f, 0.f, 0.f, 0.f};
  const int rtb = b * 256 + (m0 >> 4);  // global row-tile of xf
#pragma unroll
  for (int ks = 0; ks < 10; ks++) {
    bf16x8 af[2], bfr[4];
#pragma unroll
    for (int mi = 0; mi < 2; mi++)
      af[mi] = *(const bf16x8*)(Xf + ((size_t)(rtb + mi) * 40 + ks * 4 + lq) * 128 + lr * 8);
#pragma unroll
    for (int ni = 0; ni < 4; ni++)
      bfr[ni] = *(const bf16x8*)(Bl + ((ni * 40) + ks * 4 + lq) * 128 + lr * 8);
#pragma unroll
    for (int mi = 0; mi < 2; mi++)
#pragma unroll
      for (int ni = 0; ni < 4; ni++)
        qacc[mi][ni] =
            __builtin_amdgcn_mfma_f32_16x16x32_bf16(af[mi], bfr[ni], qacc[mi][ni], 0, 0, 0);
  }
  __syncthreads();  // all Wq reads done before Ql overwrites the region

  // ---- Phase 3: bias+scale -> bf16, swizzled LDS transpose -> qf ----
  unsigned short* Ql = (unsigned short*)smem;  // [128][64], 16 KB
  float qbv[4];
#pragma unroll
  for (int ni = 0; ni < 4; ni++) qbv[ni] = q_b[h * 64 + ni * 16 + lr];
#pragma unroll
  for (int mt = 0; mt < 2; mt++)
#pragma unroll
    for (int ni = 0; ni < 4; ni++)
#pragma unroll
      for (int rr = 0; rr < 4; rr++) {
        int row = w * 32 + mt * 16 + lq * 4 + rr;
        int col = ni * 16 + lr;
        float qv = (qacc[mt][ni][rr] + qbv[ni]) * S2;
        Ql[row * 64 + (((col >> 3) ^ (row & 7)) * 8) + (col & 7)] = f2bf(qv);
      }
  __syncthreads();
  bf16x8 qf[2][2];
#pragma unroll
  for (int mt = 0; mt < 2; mt++)
#pragma unroll
    for (int t2 = 0; t2 < 2; t2++) {
      int row = w * 32 + mt * 16 + lr;
      qf[mt][t2] = *(const bf16x8*)(Ql + row * 64 + (((t2 * 4 + lq) ^ (lr & 7)) * 8));
    }
  __syncthreads();  // qf reads done before KV staging reuses smem

  // ---- Phase 4: KV loop (R2 structure) ----
  f32x4 oacc[4][2];
  f32x2 den2[2] = {(f32x2){0.f, 0.f}, (f32x2){0.f, 0.f}};
#pragma unroll
  for (int dt = 0; dt < 4; dt++)
#pragma unroll
    for (int mt = 0; mt < 2; mt++) oacc[dt][mt] = (f32x4){0.f, 0.f, 0.f, 0.f};

  const int rS = ln >> 3, sS = ln & 7;

  auto stage = [&](int c, int buf) {
    unsigned short* KL = (unsigned short*)(smem + buf * 16384);
    unsigned short* VL = KL + 4096;
#pragma unroll
    for (int i = 0; i < 2; i++) {
      int r = (w * 2 + i) * 8 + rS;
      int g = sS ^ (r & 7);
      gl_lds16(Kp + (size_t)(c * 64 + r) * 64 + g * 8, KL + (w * 2 + i) * 512);
      gl_lds16(Vp + (size_t)r * 1024 + c * 64 + g * 8, VL + (w * 2 + i) * 512);
    }
  };

  stage(0, 0);
  __syncthreads();

  for (int c = 0; c < 16; c++) {
    if (c < 15) stage(c + 1, (c + 1) & 1);
    const unsigned short* KL = (const unsigned short*)(smem + (c & 1) * 16384);
    const unsigned short* VL = KL + 4096;

    // tp-split: compute 2 kt-tiles of S^T, exp+pack, PV — then the next 2.
#pragma unroll
    for (int tp = 0; tp < 2; tp++) {
      f32x4 sacc[2][2];
#pragma unroll
      for (int k2 = 0; k2 < 2; k2++) {
        int kt = 2 * tp + k2;
        int kr = 16 * kt + lr;
        bf16x8 kf0 = *(const bf16x8*)(KL + kr * 64 + ((lq ^ (lr & 7)) * 8));
        bf16x8 kf1 = *(const bf16x8*)(KL + kr * 64 + (((4 + lq) ^ (lr & 7)) * 8));
        __builtin_amdgcn_s_setprio(1);
#pragma unroll
        for (int mt = 0; mt < 2; mt++) {
          f32x4 s = (f32x4){0.f, 0.f, 0.f, 0.f};
          s = __builtin_amdgcn_mfma_f32_16x16x32_bf16(kf0, qf[mt][0], s, 0, 0, 0);
          s = __builtin_amdgcn_mfma_f32_16x16x32_bf16(kf1, qf[mt][1], s, 0, 0, 0);
          sacc[k2][mt] = s;
        }
        __builtin_amdgcn_s_setprio(0);
      }

      bf16x8 pf8[2];
#pragma unroll
      for (int mt = 0; mt < 2; mt++) {
        f32x4 ea, eb;
#pragma unroll
        for (int j = 0; j < 4; j++) {
          ea[j] = fast_exp2(sacc[0][mt][j]);
          eb[j] = fast_exp2(sacc[1][mt][j]);
        }
        den2[mt] += (f32x2){ea[0], ea[1]} + (f32x2){ea[2], ea[3]};
        den2[mt] += (f32x2){eb[0], eb[1]} + (f32x2){eb[2], eb[3]};
        u32x4 pk = {pkbf(ea[0], ea[1]), pkbf(ea[2], ea[3]),
                    pkbf(eb[0], eb[1]), pkbf(eb[2], eb[3])};
        pf8[mt] = __builtin_bit_cast(bf16x8, pk);
      }
#pragma unroll
      for (int dt = 0; dt < 4; dt++) {
        int vr = dt * 16 + lr;
        bf16x8 vf8 = *(const bf16x8*)(VL + vr * 64 + (((4 * tp + lq) ^ (lr & 7)) * 8));
        __builtin_amdgcn_s_setprio(1);
#pragma unroll
        for (int mt = 0; mt < 2; mt++)
          oacc[dt][mt] =
              __builtin_amdgcn_mfma_f32_16x16x32_bf16(vf8, pf8[mt], oacc[dt][mt], 0, 0, 0);
        __builtin_amdgcn_s_setprio(0);
      }
    }
    __syncthreads();
  }

  float inv[2];
#pragma unroll
  for (int mt = 0; mt < 2; mt++) {
    float s = den2[mt][0] + den2[mt][1];
    s += __shfl_xor(s, 16);
    s += __shfl_xor(s, 32);
    inv[mt] = 1.f / s;
  }

  const int rt0 = b * 256 + (m0 >> 4);
#pragma unroll
  for (int mt = 0; mt < 2; mt++)
#pragma unroll
    for (int dt = 0; dt < 4; dt++) {
      float i0 = inv[mt];
      u32x2 pk = {pkbf(oacc[dt][mt][0] * i0, oacc[dt][mt][1] * i0),
                  pkbf(oacc[dt][mt][2] * i0, oacc[dt][mt][3] * i0)};
      int colg = h * 8 + dt * 2 + (lq >> 1);
      size_t off = ((size_t)(rt0 + mt) * 40 + colg) * 128 + lr * 8 + (lq & 1) * 4;
      *(u32x2*)(AO + off) = pk;
    }
}

// ---------------------------------------------------------------------------
extern "C" void kernel_launch(void* const* d_in, const int* in_sizes, int n_in,
                              void* d_out, int out_size, void* d_ws, size_t ws_size,
                              hipStream_t stream) {
  (void)in_sizes; (void)n_in; (void)out_size; (void)ws_size;
  const float* x      = (const float*)d_in[0];
  const float* q_w    = (const float*)d_in[1];
  const float* q_b    = (const float*)d_in[2];
  const float* kv_w   = (const float*)d_in[3];
  const float* kv_b   = (const float*)d_in[4];
  const float* sr_w   = (const float*)d_in[5];
  const float* sr_b   = (const float*)d_in[6];
  const float* ln_g   = (const float*)d_in[7];
  const float* ln_b   = (const float*)d_in[8];
  const float* proj_w = (const float*)d_in[9];
  const float* proj_b = (const float*)d_in[10];
  float* out = (float*)d_out;

  char* ws = (char*)d_ws;
  size_t off = 0;
  auto alloc = [&](size_t bytes) {
    void* p = ws + off;
    off += (bytes + 255) & ~(size_t)255;
    return p;
  };
  unsigned short* xbf_fr = (unsigned short*)alloc((size_t)32768 * 320 * 2);
  unsigned short* AO     = (unsigned short*)alloc((size_t)32768 * 320 * 2);
  unsigned short* KbP    = (unsigned short*)alloc((size_t)40 * 65536 * 2);
  unsigned short* VtP    = (unsigned short*)alloc((size_t)40 * 65536 * 2);
  float*          xc     = (float*)alloc((size_t)8192 * 320 * 4);
  unsigned short* xr     = (unsigned short*)alloc((size_t)8192 * 320 * 2);
  unsigned short* Wq_fr  = (unsigned short*)alloc((size_t)320 * 320 * 2);
  unsigned short* Wkv_fr = (unsigned short*)alloc((size_t)640 * 320 * 2);
  unsigned short* Wp_fr  = (unsigned short*)alloc((size_t)320 * 320 * 2);
  unsigned short* Wsr_fr = (unsigned short*)alloc((size_t)320 * 1280 * 2);

  k_prep<<<512, 256, 0, stream>>>(x, xbf_fr);
  k_transpose_all<<<dim3(40, 20, 4), dim3(32, 8), 0, stream>>>(
      q_w, kv_w, proj_w, sr_w, Wq_fr, Wkv_fr, Wp_fr, Wsr_fr);

  // SR conv: M=8192, MT=2 -> 128 rows/block, 4 (kh,kw) segments (R6 geometry)
  k_gemm<2, 1, 3, 4><<<dim3(64, 5), 256, 0, stream>>>(xbf_fr, Wsr_fr, sr_b, xc, nullptr, 1.f);
  k_ln<<<2048, 256, 0, stream>>>(xc, ln_g, ln_b, xr);
  // KV: M=8192, MT=2 (R6 geometry)
  k_gemm<2, 0, 4, 1><<<dim3(64, 10), 256, 0, stream>>>(xr, Wkv_fr, kv_b, KbP, VtP, 1.f);
  k_attn<<<dim3(32, 40), 256, 0, stream>>>(xbf_fr, Wq_fr, q_b, KbP, VtP, AO);
  // proj: M=32768, MT=4 (R6 geometry)
  k_gemm<4, 0, 3, 1><<<dim3(128, 5), 256, 0, stream>>>(AO, Wp_fr, proj_b, out, nullptr, 1.f);
}

// Round 11
// 213.327 us; speedup vs baseline: 1.0488x; 1.0038x over previous
//
#include <hip/hip_runtime.h>

typedef __attribute__((ext_vector_type(8))) short bf16x8;
typedef __attribute__((ext_vector_type(4))) short bf16x4;
typedef __attribute__((ext_vector_type(4))) float f32x4;
typedef __attribute__((ext_vector_type(2))) float f32x2;
typedef __attribute__((ext_vector_type(2))) unsigned u32x2;
typedef __attribute__((ext_vector_type(4))) unsigned u32x4;

#define DEVI static __device__ __forceinline__
#define AS1 __attribute__((address_space(1)))
#define AS3 __attribute__((address_space(3)))

DEVI unsigned short f2bf(float f) {
  unsigned u = __builtin_bit_cast(unsigned, f);
  return (unsigned short)((u + 0x7FFFu + ((u >> 16) & 1u)) >> 16);
}

DEVI unsigned pkbf(float a, float b) {
#if __has_builtin(__builtin_amdgcn_cvt_pk_bf16_f32)
  return __builtin_bit_cast(unsigned, __builtin_amdgcn_cvt_pk_bf16_f32(a, b));
#else
  return (unsigned)f2bf(a) | ((unsigned)f2bf(b) << 16);
#endif
}

DEVI float fast_exp2(float x) {
#if __has_builtin(__builtin_amdgcn_exp2f)
  return __builtin_amdgcn_exp2f(x);
#else
  return exp2f(x);
#endif
}

// async 16B global->LDS; LDS dest = uniform base + lane*16
DEVI void gl_lds16(const unsigned short* g, unsigned short* l) {
  __builtin_amdgcn_global_load_lds((const AS1 unsigned int*)g, (AS3 unsigned int*)l, 16, 0, 0);
}

// fragment-major element offset: [row-tile16][k-granule8][16 rows][8 k]
DEVI size_t frag_off(int row, int k, int KG) {
  return ((size_t)(row >> 4) * KG + (k >> 3)) * 128 + (row & 15) * 8 + (k & 7);
}

// ---------------------------------------------------------------------------
// x fp32 [32768][320] -> bf16 fragment-major, fully coalesced via LDS bounce.
// ---------------------------------------------------------------------------
__global__ __launch_bounds__(256)
void k_prep(const float* __restrict__ x, unsigned short* __restrict__ xf) {
  __shared__ __align__(16) unsigned short L[20480];
  const int t = threadIdx.x;
  const size_t base = (size_t)blockIdx.x * 64 * 320;
#pragma unroll
  for (int i = 0; i < 10; i++) {
    int c = i * 256 + t;  // 16B granule in row-major order: r = c/40, g = c%40
    const float* p = x + base + (size_t)c * 8;
    f32x4 a = ((const f32x4*)p)[0], b = ((const f32x4*)p)[1];
    u32x4 pk = {pkbf(a[0], a[1]), pkbf(a[2], a[3]), pkbf(b[0], b[1]), pkbf(b[2], b[3])};
    int r = c / 40, g = c - r * 40;
    int gidx = ((r >> 4) * 40 + g) * 16 + (r & 15);
    int sidx = gidx ^ ((gidx >> 4) & 7);
    *(u32x4*)(L + sidx * 8) = pk;
  }
  __syncthreads();
  unsigned short* outb = xf + base;  // block's frag-region is contiguous
#pragma unroll
  for (int i = 0; i < 10; i++) {
    int o = i * 256 + t;
    int sidx = o ^ ((o >> 4) & 7);
    *(u32x4*)(outb + (size_t)o * 8) = *(const u32x4*)(L + sidx * 8);
  }
}

// ---------------------------------------------------------------------------
// Weight transposes -> bf16 fragment-major. src fp32 [K][N] -> frag[n][k].
// ---------------------------------------------------------------------------
__global__ __launch_bounds__(256)
void k_transpose_all(const float* __restrict__ q_w, const float* __restrict__ kv_w,
                     const float* __restrict__ proj_w, const float* __restrict__ sr_w,
                     unsigned short* __restrict__ Wq, unsigned short* __restrict__ Wkv,
                     unsigned short* __restrict__ Wp, unsigned short* __restrict__ Wsr) {
  const float* src; unsigned short* dst; int K, N;
  switch (blockIdx.z) {
    case 0:  src = q_w;    dst = Wq;  K = 320;  N = 320; break;
    case 1:  src = kv_w;   dst = Wkv; K = 320;  N = 640; break;
    case 2:  src = proj_w; dst = Wp;  K = 320;  N = 320; break;
    default: src = sr_w;   dst = Wsr; K = 1280; N = 320; break;
  }
  if ((int)blockIdx.x >= (K >> 5) || (int)blockIdx.y >= (N >> 5)) return;
  const int KG = K >> 3;
  __shared__ float tile[32][33];
  const int k0 = blockIdx.x * 32, n0 = blockIdx.y * 32;
  const int tx = threadIdx.x, ty = threadIdx.y;
#pragma unroll
  for (int i = 0; i < 4; i++)
    tile[ty + i * 8][tx] = src[(size_t)(k0 + ty + i * 8) * N + n0 + tx];
  __syncthreads();
#pragma unroll
  for (int i = 0; i < 4; i++) {
    int n = n0 + ty + i * 8, k = k0 + tx;
    dst[frag_off(n, k, KG)] = f2bf(tile[tx][ty + i * 8]);
  }
}

// ---------------------------------------------------------------------------
// LayerNorm: one wave per row of xc[8192][320] -> bf16 frag-major xr
// ---------------------------------------------------------------------------
__global__ __launch_bounds__(256)
void k_ln(const float* __restrict__ xc, const float* __restrict__ gam,
          const float* __restrict__ bet, unsigned short* __restrict__ xr) {
  const int row = blockIdx.x * 4 + (threadIdx.x >> 6);
  const int l = threadIdx.x & 63;
  const float* p = xc + (size_t)row * 320;
  float s = 0.f, ss = 0.f;
#pragma unroll
  for (int i = 0; i < 5; i++) { float v = p[l + 64 * i]; s += v; ss += v * v; }
#pragma unroll
  for (int o = 1; o < 64; o <<= 1) { s += __shfl_xor(s, o); ss += __shfl_xor(ss, o); }
  float mu = s * (1.f / 320.f);
  float var = ss * (1.f / 320.f) - mu * mu;
  float rstd = rsqrtf(var + 1e-5f);
  if (l < 40) {
    f32x4 a = ((const f32x4*)(p + l * 8))[0], b = ((const f32x4*)(p + l * 8))[1];
    f32x4 ga = ((const f32x4*)(gam + l * 8))[0], gb = ((const f32x4*)(gam + l * 8))[1];
    f32x4 ba = ((const f32x4*)(bet + l * 8))[0], bb = ((const f32x4*)(bet + l * 8))[1];
    f32x4 ya, yb;
#pragma unroll
    for (int j = 0; j < 4; j++) {
      ya[j] = (a[j] - mu) * rstd * ga[j] + ba[j];
      yb[j] = (b[j] - mu) * rstd * gb[j] + bb[j];
    }
    u32x4 pk = {pkbf(ya[0], ya[1]), pkbf(ya[2], ya[3]), pkbf(yb[0], yb[1]), pkbf(yb[2], yb[3])};
    *(u32x4*)(xr + ((size_t)((row >> 4) * 40 + l)) * 128 + (row & 15) * 8) = pk;
  }
}

// ---------------------------------------------------------------------------
// Weights-stationary GEMM (R6 geometry — best measured).
// AK: 0 = A frag-major rows;  1 = SR-conv row-remap (NSEG=4 (kh,kw) segments)
// EPI: 3 = fp32 out [M][320]
//      4 = KV merged: n0<320 -> Kb; else Vt [b][h][64][1024] (LDS bounce),
//          kv-permuted so the attention PV A-fragment is one 16B granule.
// ---------------------------------------------------------------------------
template <int MT, int AK, int EPI, int NSEG>
__global__ __launch_bounds__(256)
void k_gemm(const unsigned short* __restrict__ A, const unsigned short* __restrict__ W,
            const float* __restrict__ bias, void* __restrict__ outp, void* __restrict__ outp2,
            float oscale) {
  __shared__ __align__(16) unsigned short Bl[20480];  // 40 KB
  const int t = threadIdx.x, w = t >> 6, ln = t & 63, lr = ln & 15, lq = ln >> 4;
  const int m0 = blockIdx.x * (MT * 64), n0 = blockIdx.y * 64;

  f32x4 acc[MT][4];
#pragma unroll
  for (int i = 0; i < MT; i++)
#pragma unroll
    for (int j = 0; j < 4; j++) acc[i][j] = (f32x4){0.f, 0.f, 0.f, 0.f};

#pragma unroll
  for (int seg = 0; seg < NSEG; seg++) {
    const int kh = seg >> 1, kw = seg & 1;
    if (seg) __syncthreads();
    if (AK == 0) {
      const unsigned short* Ws = W + ((size_t)(n0 >> 4) * 40) * 128;
#pragma unroll
      for (int j = 0; j < 10; j++)
        gl_lds16(Ws + (size_t)(j * 4 + w) * 512 + ln * 8, Bl + (j * 4 + w) * 512);
    } else {
      const unsigned short* Wt = W + ((size_t)((n0 >> 4) + w) * 160 + seg * 40) * 128;
#pragma unroll
      for (int j = 0; j < 10; j++)
        gl_lds16(Wt + (size_t)j * 512 + ln * 8, Bl + w * 5120 + j * 512);
    }
    __syncthreads();

#pragma unroll
    for (int ks = 0; ks < 10; ks++) {
      bf16x8 af[MT], bfr[4];
#pragma unroll
      for (int mi = 0; mi < MT; mi++) {
        if (AK == 0) {
          af[mi] = *(const bf16x8*)(
              A + ((size_t)((m0 >> 4) + w * MT + mi) * 40 + ks * 4 + lq) * 128 + lr * 8);
        } else {
          int gm = m0 + (w * MT + mi) * 16;
          int b = gm >> 10, p = gm & 1023, oy = p >> 5, ox0 = p & 31;
          int r0 = (2 * oy + kh) * 64 + 2 * ox0 + kw;           // r0 & 15 == kw
          int brt = b * 256 + (r0 >> 4);
          af[mi] = *(const bf16x8*)(
              A + ((size_t)(brt + (lr >> 3)) * 40 + ks * 4 + lq) * 128 +
              (kw + 2 * (lr & 7)) * 8);
        }
      }
#pragma unroll
      for (int ni = 0; ni < 4; ni++)
        bfr[ni] = *(const bf16x8*)(Bl + ((ni * 40) + ks * 4 + lq) * 128 + lr * 8);
#pragma unroll
      for (int mi = 0; mi < MT; mi++)
#pragma unroll
        for (int ni = 0; ni < 4; ni++)
          acc[mi][ni] =
              __builtin_amdgcn_mfma_f32_16x16x32_bf16(af[mi], bfr[ni], acc[mi][ni], 0, 0, 0);
    }
  }

  if (EPI == 3) {  // fp32 [M][320]
    float* out = (float*)outp;
#pragma unroll
    for (int mi = 0; mi < MT; mi++)
#pragma unroll
      for (int ni = 0; ni < 4; ni++)
#pragma unroll
        for (int rr = 0; rr < 4; rr++) {
          int gm = m0 + (w * MT + mi) * 16 + lq * 4 + rr;
          int gc = n0 + ni * 16 + lr;
          out[(size_t)gm * 320 + gc] = acc[mi][ni][rr] + bias[gc];
        }
  } else {  // EPI == 4: KV merged
    if (n0 < 320) {  // K -> [b][h][1024][64]
      unsigned short* out = (unsigned short*)outp;
      const int h = n0 >> 6;
#pragma unroll
      for (int mi = 0; mi < MT; mi++)
#pragma unroll
        for (int ni = 0; ni < 4; ni++)
#pragma unroll
          for (int rr = 0; rr < 4; rr++) {
            int gm = m0 + (w * MT + mi) * 16 + lq * 4 + rr;
            int b = gm >> 10, mm = gm & 1023, d = ni * 16 + lr;
            out[((size_t)(b * 5 + h) << 16) + ((size_t)mm << 6) + d] =
                f2bf(acc[mi][ni][rr] + bias[n0 + d]);
          }
    } else {  // V -> [b][h][64][1024] via LDS bounce (block = MT*64 rows)
      unsigned short* out = (unsigned short*)outp2;
      const int h = (n0 - 320) >> 6;
      const int LDT = MT * 64 + 8;
      unsigned short* Tl = (unsigned short*)Bl;  // [64][LDT]
      __syncthreads();
#pragma unroll
      for (int mi = 0; mi < MT; mi++)
#pragma unroll
        for (int ni = 0; ni < 4; ni++)
#pragma unroll
          for (int rr = 0; rr < 4; rr++) {
            int ml = (w * MT + mi) * 16 + lq * 4 + rr;  // 0..MT*64-1
            int d = ni * 16 + lr;
            Tl[d * LDT + ml] = f2bf(acc[mi][ni][rr] + bias[n0 + d]);
          }
      __syncthreads();
      const int b = m0 >> 10, mm0 = m0 & 1023;
#pragma unroll
      for (int i = 0; i < 2 * MT; i++) {
        int ch = t + 256 * i, d = ch / (8 * MT), g = ch % (8 * MT);
        int c2 = g >> 2, ns = g & 3;  // kv-permute: {4-elem lo, 4-elem hi}
        const unsigned short* src = Tl + d * LDT + c2 * 32 + ns * 4;
        bf16x4 lo = *(const bf16x4*)(src);
        bf16x4 hi = *(const bf16x4*)(src + 16);
        bf16x8 v8 = {lo[0], lo[1], lo[2], lo[3], hi[0], hi[1], hi[2], hi[3]};
        *(bf16x8*)(out + ((size_t)(b * 5 + h) << 16) + d * 1024 + mm0 + g * 8) = v8;
      }
    }
  }
}

// ---------------------------------------------------------------------------
// Attention with FUSED Q projection. LDS shrunk to 32 KB so 5 blocks/CU
// co-reside: grid = 1280 blocks = 256 CUs x 5 -> exactly ONE generation
// (the 4-block config ran 1.25 generations; measured Occ 30% == (16+4)/2).
// Wq staged in two 16 KB halves (kg 0..19 then 20..39, compacted ni*20+kg).
// KV loop unchanged (2 x 16 KB double buffer).
// ---------------------------------------------------------------------------
__global__ __launch_bounds__(256, 5)
void k_attn(const unsigned short* __restrict__ Xf, const unsigned short* __restrict__ Wq,
            const float* __restrict__ q_b,
            const unsigned short* __restrict__ Kb, const unsigned short* __restrict__ Vt,
            unsigned short* __restrict__ AO) {
  __shared__ __align__(16) unsigned char smem[32768];  // Wq-half 16KB / Ql 16KB / KV 2x16KB
  const int t = threadIdx.x, w = t >> 6, ln = t & 63, lr = ln & 15, lq = ln >> 4;
  const int bh = blockIdx.y;
  const int b = bh / 5, h = bh - b * 5;
  const int m0 = blockIdx.x * 128 + w * 32;  // local row within (b, ...)
  const unsigned short* Kp = Kb + ((size_t)bh << 16);
  const unsigned short* Vp = Vt + ((size_t)bh << 16);
  const float S2 = 0.125f * 1.4426950408889634f;  // SCALE * log2(e)

  // ---- Phase 1+2: Q = x @ Wq^T, Wq staged in two 16 KB halves ----
  unsigned short* Bl = (unsigned short*)smem;
  const unsigned short* Ws = Wq + ((size_t)(h * 4) * 40) * 128;  // h-slice base
  f32x4 qacc[2][4];
#pragma unroll
  for (int mi = 0; mi < 2; mi++)
#pragma unroll
    for (int ni = 0; ni < 4; ni++) qacc[mi][ni] = (f32x4){0.f, 0.f, 0.f, 0.f};
  const int rtb = b * 256 + (m0 >> 4);  // global row-tile of xf

#pragma unroll
  for (int H = 0; H < 2; H++) {
    if (H) __syncthreads();  // all reads of half 0 done before overwrite
    // stage half H: units u = w*10 + 5H + j5 (wave w owns column-tile w)
#pragma unroll
    for (int j5 = 0; j5 < 5; j5++)
      gl_lds16(Ws + (size_t)(w * 10 + 5 * H + j5) * 512 + ln * 8,
               Bl + (size_t)w * 2560 + j5 * 512);
    __syncthreads();
#pragma unroll
    for (int ksub = 0; ksub < 5; ksub++) {
      int ks = 5 * H + ksub;
      bf16x8 af[2], bfr[4];
#pragma unroll
      for (int mi = 0; mi < 2; mi++)
        af[mi] = *(const bf16x8*)(Xf + ((size_t)(rtb + mi) * 40 + ks * 4 + lq) * 128 + lr * 8);
#pragma unroll
      for (int ni = 0; ni < 4; ni++)
        bfr[ni] = *(const bf16x8*)(Bl + ((ni * 20) + ksub * 4 + lq) * 128 + lr * 8);
#pragma unroll
      for (int mi = 0; mi < 2; mi++)
#pragma unroll
        for (int ni = 0; ni < 4; ni++)
          qacc[mi][ni] =
              __builtin_amdgcn_mfma_f32_16x16x32_bf16(af[mi], bfr[ni], qacc[mi][ni], 0, 0, 0);
    }
  }
  __syncthreads();  // all Wq reads done before Ql overwrites the region

  // ---- Phase 3: bias+scale -> bf16, swizzled LDS transpose -> qf ----
  unsigned short* Ql = (unsigned short*)smem;  // [128][64], 16 KB
  float qbv[4];
#pragma unroll
  for (int ni = 0; ni < 4; ni++) qbv[ni] = q_b[h * 64 + ni * 16 + lr];
#pragma unroll
  for (int mt = 0; mt < 2; mt++)
#pragma unroll
    for (int ni = 0; ni < 4; ni++)
#pragma unroll
      for (int rr = 0; rr < 4; rr++) {
        int row = w * 32 + mt * 16 + lq * 4 + rr;
        int col = ni * 16 + lr;
        float qv = (qacc[mt][ni][rr] + qbv[ni]) * S2;
        Ql[row * 64 + (((col >> 3) ^ (row & 7)) * 8) + (col & 7)] = f2bf(qv);
      }
  __syncthreads();
  bf16x8 qf[2][2];
#pragma unroll
  for (int mt = 0; mt < 2; mt++)
#pragma unroll
    for (int t2 = 0; t2 < 2; t2++) {
      int row = w * 32 + mt * 16 + lr;
      qf[mt][t2] = *(const bf16x8*)(Ql + row * 64 + (((t2 * 4 + lq) ^ (lr & 7)) * 8));
    }
  __syncthreads();  // qf reads done before KV staging reuses smem

  // ---- Phase 4: KV loop (R2 structure) ----
  f32x4 oacc[4][2];
  f32x2 den2[2] = {(f32x2){0.f, 0.f}, (f32x2){0.f, 0.f}};
#pragma unroll
  for (int dt = 0; dt < 4; dt++)
#pragma unroll
    for (int mt = 0; mt < 2; mt++) oacc[dt][mt] = (f32x4){0.f, 0.f, 0.f, 0.f};

  const int rS = ln >> 3, sS = ln & 7;

  auto stage = [&](int c, int buf) {
    unsigned short* KL = (unsigned short*)(smem + buf * 16384);
    unsigned short* VL = KL + 4096;
#pragma unroll
    for (int i = 0; i < 2; i++) {
      int r = (w * 2 + i) * 8 + rS;
      int g = sS ^ (r & 7);
      gl_lds16(Kp + (size_t)(c * 64 + r) * 64 + g * 8, KL + (w * 2 + i) * 512);
      gl_lds16(Vp + (size_t)r * 1024 + c * 64 + g * 8, VL + (w * 2 + i) * 512);
    }
  };

  stage(0, 0);
  __syncthreads();

  for (int c = 0; c < 16; c++) {
    if (c < 15) stage(c + 1, (c + 1) & 1);
    const unsigned short* KL = (const unsigned short*)(smem + (c & 1) * 16384);
    const unsigned short* VL = KL + 4096;

    // tp-split: compute 2 kt-tiles of S^T, exp+pack, PV — then the next 2.
#pragma unroll
    for (int tp = 0; tp < 2; tp++) {
      f32x4 sacc[2][2];
#pragma unroll
      for (int k2 = 0; k2 < 2; k2++) {
        int kt = 2 * tp + k2;
        int kr = 16 * kt + lr;
        bf16x8 kf0 = *(const bf16x8*)(KL + kr * 64 + ((lq ^ (lr & 7)) * 8));
        bf16x8 kf1 = *(const bf16x8*)(KL + kr * 64 + (((4 + lq) ^ (lr & 7)) * 8));
        __builtin_amdgcn_s_setprio(1);
#pragma unroll
        for (int mt = 0; mt < 2; mt++) {
          f32x4 s = (f32x4){0.f, 0.f, 0.f, 0.f};
          s = __builtin_amdgcn_mfma_f32_16x16x32_bf16(kf0, qf[mt][0], s, 0, 0, 0);
          s = __builtin_amdgcn_mfma_f32_16x16x32_bf16(kf1, qf[mt][1], s, 0, 0, 0);
          sacc[k2][mt] = s;
        }
        __builtin_amdgcn_s_setprio(0);
      }

      bf16x8 pf8[2];
#pragma unroll
      for (int mt = 0; mt < 2; mt++) {
        f32x4 ea, eb;
#pragma unroll
        for (int j = 0; j < 4; j++) {
          ea[j] = fast_exp2(sacc[0][mt][j]);
          eb[j] = fast_exp2(sacc[1][mt][j]);
        }
        den2[mt] += (f32x2){ea[0], ea[1]} + (f32x2){ea[2], ea[3]};
        den2[mt] += (f32x2){eb[0], eb[1]} + (f32x2){eb[2], eb[3]};
        u32x4 pk = {pkbf(ea[0], ea[1]), pkbf(ea[2], ea[3]),
                    pkbf(eb[0], eb[1]), pkbf(eb[2], eb[3])};
        pf8[mt] = __builtin_bit_cast(bf16x8, pk);
      }
#pragma unroll
      for (int dt = 0; dt < 4; dt++) {
        int vr = dt * 16 + lr;
        bf16x8 vf8 = *(const bf16x8*)(VL + vr * 64 + (((4 * tp + lq) ^ (lr & 7)) * 8));
        __builtin_amdgcn_s_setprio(1);
#pragma unroll
        for (int mt = 0; mt < 2; mt++)
          oacc[dt][mt] =
              __builtin_amdgcn_mfma_f32_16x16x32_bf16(vf8, pf8[mt], oacc[dt][mt], 0, 0, 0);
        __builtin_amdgcn_s_setprio(0);
      }
    }
    __syncthreads();
  }

  float inv[2];
#pragma unroll
  for (int mt = 0; mt < 2; mt++) {
    float s = den2[mt][0] + den2[mt][1];
    s += __shfl_xor(s, 16);
    s += __shfl_xor(s, 32);
    inv[mt] = 1.f / s;
  }

  const int rt0 = b * 256 + (m0 >> 4);
#pragma unroll
  for (int mt = 0; mt < 2; mt++)
#pragma unroll
    for (int dt = 0; dt < 4; dt++) {
      float i0 = inv[mt];
      u32x2 pk = {pkbf(oacc[dt][mt][0] * i0, oacc[dt][mt][1] * i0),
                  pkbf(oacc[dt][mt][2] * i0, oacc[dt][mt][3] * i0)};
      int colg = h * 8 + dt * 2 + (lq >> 1);
      size_t off = ((size_t)(rt0 + mt) * 40 + colg) * 128 + lr * 8 + (lq & 1) * 4;
      *(u32x2*)(AO + off) = pk;
    }
}

// ---------------------------------------------------------------------------
extern "C" void kernel_launch(void* const* d_in, const int* in_sizes, int n_in,
                              void* d_out, int out_size, void* d_ws, size_t ws_size,
                              hipStream_t stream) {
  (void)in_sizes; (void)n_in; (void)out_size; (void)ws_size;
  const float* x      = (const float*)d_in[0];
  const float* q_w    = (const float*)d_in[1];
  const float* q_b    = (const float*)d_in[2];
  const float* kv_w   = (const float*)d_in[3];
  const float* kv_b   = (const float*)d_in[4];
  const float* sr_w   = (const float*)d_in[5];
  const float* sr_b   = (const float*)d_in[6];
  const float* ln_g   = (const float*)d_in[7];
  const float* ln_b   = (const float*)d_in[8];
  const float* proj_w = (const float*)d_in[9];
  const float* proj_b = (const float*)d_in[10];
  float* out = (float*)d_out;

  char* ws = (char*)d_ws;
  size_t off = 0;
  auto alloc = [&](size_t bytes) {
    void* p = ws + off;
    off += (bytes + 255) & ~(size_t)255;
    return p;
  };
  unsigned short* xbf_fr = (unsigned short*)alloc((size_t)32768 * 320 * 2);
  unsigned short* AO     = (unsigned short*)alloc((size_t)32768 * 320 * 2);
  unsigned short* KbP    = (unsigned short*)alloc((size_t)40 * 65536 * 2);
  unsigned short* VtP    = (unsigned short*)alloc((size_t)40 * 65536 * 2);
  float*          xc     = (float*)alloc((size_t)8192 * 320 * 4);
  unsigned short* xr     = (unsigned short*)alloc((size_t)8192 * 320 * 2);
  unsigned short* Wq_fr  = (unsigned short*)alloc((size_t)320 * 320 * 2);
  unsigned short* Wkv_fr = (unsigned short*)alloc((size_t)640 * 320 * 2);
  unsigned short* Wp_fr  = (unsigned short*)alloc((size_t)320 * 320 * 2);
  unsigned short* Wsr_fr = (unsigned short*)alloc((size_t)320 * 1280 * 2);

  k_prep<<<512, 256, 0, stream>>>(x, xbf_fr);
  k_transpose_all<<<dim3(40, 20, 4), dim3(32, 8), 0, stream>>>(
      q_w, kv_w, proj_w, sr_w, Wq_fr, Wkv_fr, Wp_fr, Wsr_fr);

  // SR conv: M=8192, MT=2 -> 128 rows/block, 4 (kh,kw) segments (R6 geometry)
  k_gemm<2, 1, 3, 4><<<dim3(64, 5), 256, 0, stream>>>(xbf_fr, Wsr_fr, sr_b, xc, nullptr, 1.f);
  k_ln<<<2048, 256, 0, stream>>>(xc, ln_g, ln_b, xr);
  // KV: M=8192, MT=2 (R6 geometry)
  k_gemm<2, 0, 4, 1><<<dim3(64, 10), 256, 0, stream>>>(xr, Wkv_fr, kv_b, KbP, VtP, 1.f);
  k_attn<<<dim3(32, 40), 256, 0, stream>>>(xbf_fr, Wq_fr, q_b, KbP, VtP, AO);
  // proj: M=32768, MT=4 (R6 geometry)
  k_gemm<4, 0, 3, 1><<<dim3(128, 5), 256, 0, stream>>>(AO, Wp_fr, proj_b, out, nullptr, 1.f);
}